// Round 1
// baseline (385.454 us; speedup 1.0000x reference)
//
#include <hip/hip_runtime.h>

// Problem constants (from reference)
#define NB   32
#define NT   128
#define NC   64
#define NF   64
#define NK   128
#define NKH  3
#define NCP  62            // NC - NKH + 1
#define NJ   192           // NKH * NF  (reduction length)
#define LDSF 65            // padded row stride for x tile (+1 breaks bank aliasing)
#define BN_EPS 1e-3f

// y[bt, cp, k] = relu( (sum_j x[bt, cp*64 + j] * w[j,k] + bias[k]) * scale[t] + shift[t] )
// where j indexes 192 contiguous floats of the x slice starting at row cp,
// and w is conv_w viewed as row-major (192, 128).
__global__ __launch_bounds__(256) void tccnn_fwd(
    const float* __restrict__ x, const float* __restrict__ w,
    const float* __restrict__ bias, const float* __restrict__ gamma,
    const float* __restrict__ beta, const float* __restrict__ mean,
    const float* __restrict__ var, float* __restrict__ out)
{
    __shared__ float xs[NC * LDSF];

    const int bt  = blockIdx.x;
    const int tid = threadIdx.x;
    const int t   = bt & (NT - 1);

    // Stage the 64x64 fp32 x-slice into LDS (padded rows).
    const float* xbase = x + (size_t)bt * (NC * NF);
    #pragma unroll
    for (int i = 0; i < 4; ++i) {
        int idx = tid + i * 256;              // float4 index, 1024 total
        float4 v = ((const float4*)xbase)[idx];
        int c = idx >> 4;                     // (idx*4)/64
        int f = (idx * 4) & 63;
        float* dst = &xs[c * LDSF + f];
        dst[0] = v.x; dst[1] = v.y; dst[2] = v.z; dst[3] = v.w;
    }
    __syncthreads();

    const float scale = gamma[t] * rsqrtf(var[t] + BN_EPS);
    const float shift = beta[t] - mean[t] * scale;

    // Thread tile: 4 rows (cp) x 8 k-columns.
    const int kk  = tid & 15;      // 16 k-groups * 8 = 128 k
    const int rr  = tid >> 4;      // 16 row-groups * 4 = 64 rows (62 valid)
    const int k0  = kk * 8;
    const int cp0 = rr * 4;

    float acc[4][8];
    #pragma unroll
    for (int r = 0; r < 4; ++r)
        #pragma unroll
        for (int c = 0; c < 8; ++c) acc[r][c] = 0.f;

    const float* wp = w + k0;
    #pragma unroll 4
    for (int j = 0; j < NJ; ++j) {
        const int kh = j >> 6;
        const int f  = j & 63;
        const float4 w0 = ((const float4*)(wp + (size_t)j * NK))[0];
        const float4 w1 = ((const float4*)(wp + (size_t)j * NK))[1];
        #pragma unroll
        for (int r = 0; r < 4; ++r) {
            int row = cp0 + r + kh;
            row = row > (NC - 1) ? (NC - 1) : row;  // clamp; edge results discarded
            const float xv = xs[row * LDSF + f];
            acc[r][0] += xv * w0.x;
            acc[r][1] += xv * w0.y;
            acc[r][2] += xv * w0.z;
            acc[r][3] += xv * w0.w;
            acc[r][4] += xv * w1.x;
            acc[r][5] += xv * w1.y;
            acc[r][6] += xv * w1.z;
            acc[r][7] += xv * w1.w;
        }
    }

    float bv[8];
    #pragma unroll
    for (int c = 0; c < 8; ++c) bv[c] = bias[k0 + c];

    #pragma unroll
    for (int r = 0; r < 4; ++r) {
        const int cp = cp0 + r;
        if (cp < NCP) {
            float res[8];
            #pragma unroll
            for (int c = 0; c < 8; ++c) {
                float v = (acc[r][c] + bv[c]) * scale + shift;
                res[c] = v > 0.f ? v : 0.f;
            }
            float4* op = (float4*)&out[((size_t)bt * NCP + cp) * NK + k0];
            op[0] = make_float4(res[0], res[1], res[2], res[3]);
            op[1] = make_float4(res[4], res[5], res[6], res[7]);
        }
    }
}

extern "C" void kernel_launch(void* const* d_in, const int* in_sizes, int n_in,
                              void* d_out, int out_size, void* d_ws, size_t ws_size,
                              hipStream_t stream) {
    const float* x     = (const float*)d_in[0];
    const float* w     = (const float*)d_in[1];
    const float* bias  = (const float*)d_in[2];
    const float* gamma = (const float*)d_in[3];
    const float* beta  = (const float*)d_in[4];
    const float* mean  = (const float*)d_in[5];
    const float* var   = (const float*)d_in[6];
    float* out = (float*)d_out;

    tccnn_fwd<<<dim3(NB * NT), dim3(256), 0, stream>>>(
        x, w, bias, gamma, beta, mean, var, out);
}

// Round 2
// 216.144 us; speedup vs baseline: 1.7833x; 1.7833x over previous
//
#include <hip/hip_runtime.h>
#include <hip/hip_bf16.h>

// Problem constants
#define NB   32
#define NT   128
#define NC   64
#define NF   64
#define NK   128
#define NKH  3
#define NCP  62            // NC - NKH + 1
#define NJ   192           // NKH * NF (GEMM reduction length)
#define BN_EPS 1e-3f

// LDS layout (units: 16B chunks of 8 bf16)
//  x slice: 512 real chunks (+64 zero pad for edge rows 62/63), XOR-swizzled
//  wT:      128 rows x 24 chunks, padded to stride 25 (odd -> conflict-free)
#define XCHUNKS      576
#define WROW_CHUNKS  25
#define WCHUNKS      (NK * WROW_CHUNKS)   // 3200

typedef __attribute__((ext_vector_type(8))) short short8;
typedef __attribute__((ext_vector_type(4))) float floatx4;

__device__ __forceinline__ short f2bf(float f) {
    __hip_bfloat16 h = __float2bfloat16(f);
    return *reinterpret_cast<short*>(&h);
}

// chunk-index swizzle: distributes rows (8 chunks apart) across banks
__device__ __forceinline__ int swz(int c) { return c ^ ((c >> 3) & 7); }

// Pre-kernel: wT[n][j] = bf16(w[j][k=n]); wT dense 128x192 bf16 in ws.
__global__ __launch_bounds__(256) void conv_w_to_bf16T(
    const float* __restrict__ w, short* __restrict__ wT)
{
    int idx = blockIdx.x * 256 + threadIdx.x;   // 0 .. 24575
    int n = idx / NJ;
    int j = idx - n * NJ;
    wT[idx] = f2bf(w[(size_t)j * NK + n]);
}

__global__ __launch_bounds__(256) void tccnn_mfma(
    const float* __restrict__ x, const short* __restrict__ wT,
    const float* __restrict__ bias, const float* __restrict__ gamma,
    const float* __restrict__ beta, const float* __restrict__ mean,
    const float* __restrict__ var, float* __restrict__ out)
{
    __shared__ short xsh[XCHUNKS * 8];          //  9216 B
    __shared__ short wsh[WCHUNKS * 8];          // 51200 B

    const int bt  = blockIdx.x;
    const int tid = threadIdx.x;
    const int t   = bt & (NT - 1);

    short8* xs8 = (short8*)xsh;
    short8* ws8 = (short8*)wsh;

    // ---- stage x slice: 4096 f32 -> 512 bf16 chunks, swizzled ----
    const float4* xbase = (const float4*)(x + (size_t)bt * (NC * NF));
    #pragma unroll
    for (int i = 0; i < 2; ++i) {
        int c = tid + i * 256;
        float4 v0 = xbase[2 * c];
        float4 v1 = xbase[2 * c + 1];
        short8 p;
        p[0] = f2bf(v0.x); p[1] = f2bf(v0.y); p[2] = f2bf(v0.z); p[3] = f2bf(v0.w);
        p[4] = f2bf(v1.x); p[5] = f2bf(v1.y); p[6] = f2bf(v1.z); p[7] = f2bf(v1.w);
        xs8[swz(c)] = p;
    }
    if (tid < 64) {                              // zero pad (rows 62/63 overrun)
        short8 z = {0,0,0,0,0,0,0,0};
        xs8[swz(512 + tid)] = z;
    }

    // ---- stage wT: 3072 chunks -> stride-25 padded rows ----
    const short8* wTg = (const short8*)wT;
    #pragma unroll
    for (int i = 0; i < 12; ++i) {
        int g = tid + i * 256;                   // dense chunk idx
        int n = g / 24;
        int r = g - n * 24;
        ws8[n * WROW_CHUNKS + r] = wTg[g];
    }
    __syncthreads();

    // ---- MFMA main loop: wave wv computes rows 16wv..16wv+15, all 128 cols ----
    const int wv   = tid >> 6;
    const int lane = tid & 63;
    const int col  = lane & 15;                  // A row / B col / C col
    const int q    = lane >> 4;                  // k-subchunk 0..3

    const int mbase = wv * 16;
    const int arow  = mbase + col;

    floatx4 acc[8];
    #pragma unroll
    for (int nt = 0; nt < 8; ++nt) acc[nt] = (floatx4){0.f, 0.f, 0.f, 0.f};

    #pragma unroll
    for (int s = 0; s < 6; ++s) {
        short8 a = xs8[swz(8 * arow + 4 * s + q)];
        short8 b[8];
        #pragma unroll
        for (int nt = 0; nt < 8; ++nt)
            b[nt] = ws8[(nt * 16 + col) * WROW_CHUNKS + 4 * s + q];
        #pragma unroll
        for (int nt = 0; nt < 8; ++nt)
            acc[nt] = __builtin_amdgcn_mfma_f32_16x16x32_bf16(a, b[nt], acc[nt], 0, 0, 0);
    }

    // ---- epilogue: bias + BN + relu, scalar f32 stores ----
    const float scale = gamma[t] * rsqrtf(var[t] + BN_EPS);
    const float shift = beta[t] - mean[t] * scale;

    float* obase = out + (size_t)bt * (NCP * NK);
    #pragma unroll
    for (int nt = 0; nt < 8; ++nt) {
        const int k  = nt * 16 + col;
        const float bv = bias[k];
        #pragma unroll
        for (int reg = 0; reg < 4; ++reg) {
            const int cp = mbase + q * 4 + reg;  // C row
            if (cp < NCP) {
                float v = (acc[nt][reg] + bv) * scale + shift;
                obase[(size_t)cp * NK + k] = v > 0.f ? v : 0.f;
            }
        }
    }
}

extern "C" void kernel_launch(void* const* d_in, const int* in_sizes, int n_in,
                              void* d_out, int out_size, void* d_ws, size_t ws_size,
                              hipStream_t stream) {
    const float* x     = (const float*)d_in[0];
    const float* w     = (const float*)d_in[1];
    const float* bias  = (const float*)d_in[2];
    const float* gamma = (const float*)d_in[3];
    const float* beta  = (const float*)d_in[4];
    const float* mean  = (const float*)d_in[5];
    const float* var   = (const float*)d_in[6];
    float* out = (float*)d_out;
    short* wT  = (short*)d_ws;                   // 24576 bf16 = 48 KB scratch

    conv_w_to_bf16T<<<dim3(96), dim3(256), 0, stream>>>(w, wT);
    tccnn_mfma<<<dim3(NB * NT), dim3(256), 0, stream>>>(
        x, wT, bias, gamma, beta, mean, var, out);
}